// Round 10
// baseline (1369.729 us; speedup 1.0000x reference)
//
#include <hip/hip_runtime.h>
#include <math.h>

typedef _Float16 h2_t  __attribute__((ext_vector_type(2)));
typedef _Float16 h8_t  __attribute__((ext_vector_type(8)));
typedef float    f4_t  __attribute__((ext_vector_type(4)));

#define T_ 512
#define B_ 64
#define E_ 256
#define H_ 256
#define G_ 1024   // 4*H
#define K_ 16
#define NEG_ (-10000.0f)
#define START_ 14
#define STOP_ 15

#if defined(__has_builtin)
#if __has_builtin(__builtin_amdgcn_fdot2)
#define HAVE_FDOT2 1
#endif
#endif

static __device__ __forceinline__ float dot2(h2_t a, h2_t b, float c) {
#ifdef HAVE_FDOT2
    return __builtin_amdgcn_fdot2(a, b, c, false);
#else
    return fmaf((float)a[0], (float)b[0], fmaf((float)a[1], (float)b[1], c));
#endif
}

// extract h2 pair P from a wider fp16 vector — template param keeps the
// shufflevector indices integer-constant (SSA, no alloca ever).
template <int P, typename V>
static __device__ __forceinline__ h2_t get2(V v) {
    return __builtin_shufflevector(v, v, 2 * P, 2 * P + 1);
}

// ---------------------------------------------------------------------------
// Prep: pack all weights to fp16 in the layouts the hot kernels want.
//  wreg2: [d2 = dir*2+half][v=0..7][q=0..511] x 32 halves
//         (row = (q>>7)*256 + half*128 + (q&127), k = v*32)     -> 1 MB
//  wih16: [dir][row 0..1023][k 0..255] fp16 copy of w_ih        -> 1 MB
// (byte-identical to the round-1 verified version)
// ---------------------------------------------------------------------------
__global__ __launch_bounds__(256)
void prep_weights(const float* __restrict__ w_hh_f,
                  const float* __restrict__ w_hh_b,
                  const float* __restrict__ w_ih_f,
                  const float* __restrict__ w_ih_b,
                  _Float16* __restrict__ wreg2,
                  _Float16* __restrict__ wih16)
{
    const int blk = blockIdx.x, tid = threadIdx.x;
    if (blk < 64) {                       // wreg2: 16384 x h32
        int e = blk * 256 + tid;
        int q = e & 511;
        int g = e >> 9;
        int d2 = g >> 3, v = g & 7;
        int dir = d2 >> 1, half = d2 & 1;
        int row = (q >> 7) * 256 + half * 128 + (q & 127);
        const float* src = (dir ? w_hh_b : w_hh_f) + (size_t)row * 256 + v * 32;
        _Float16* dst = wreg2 + (size_t)e * 32;
        #pragma unroll
        for (int i = 0; i < 32; ++i) dst[i] = (_Float16)src[i];
    } else {                              // wih16: 65536 x h8
        int idx = (blk - 64) * 256 + tid;
        int dir = idx / 32768, rem = idx % 32768;
        const float* src = (dir ? w_ih_b : w_ih_f) + (size_t)rem * 8;
        _Float16* dst = wih16 + (size_t)idx * 8;
        #pragma unroll
        for (int i = 0; i < 8; ++i) dst[i] = (_Float16)src[i];
    }
}

// ---------------------------------------------------------------------------
// Kernel A: input-gate GEMM via f16 MFMA 16x16x32 (round-1 verified version).
// ---------------------------------------------------------------------------
__global__ __launch_bounds__(256)
void gates_mfma(const int* __restrict__ sentence,
                const float* __restrict__ emb,
                const _Float16* __restrict__ wih16,
                _Float16* __restrict__ gin_f,
                _Float16* __restrict__ gin_b)
{
    __shared__ _Float16 As[64 * 264];
    __shared__ _Float16 Bs[256 * 40];
    __shared__ int sidx[64];

    const int bm  = blockIdx.x;           // t
    const int dir = blockIdx.y;
    const int tid = threadIdx.x;

    const _Float16* __restrict__ wih = wih16 + (size_t)dir * 262144;
    _Float16* __restrict__ gout      = dir ? gin_b : gin_f;

    if (tid < 64) sidx[tid] = sentence[tid * T_ + bm];
    __syncthreads();

    {   // stage A (emb gather, fp32 -> fp16)
        const int r = tid & 63, kq = tid >> 6;
        const float4* src = (const float4*)(emb + (size_t)sidx[r] * 256 + kq * 64);
        _Float16* dst = As + r * 264 + kq * 64;
        #pragma unroll
        for (int c = 0; c < 8; ++c) {
            float4 v0 = src[2 * c], v1 = src[2 * c + 1];
            h8_t o;
            o[0] = (_Float16)v0.x; o[1] = (_Float16)v0.y;
            o[2] = (_Float16)v0.z; o[3] = (_Float16)v0.w;
            o[4] = (_Float16)v1.x; o[5] = (_Float16)v1.y;
            o[6] = (_Float16)v1.z; o[7] = (_Float16)v1.w;
            *(h8_t*)(dst + c * 8) = o;
        }
    }

    const int wave = tid >> 6, lane = tid & 63;
    const int l15 = lane & 15, quad = lane >> 4;

    for (int pass = 0; pass < 4; ++pass) {
        const int n0 = pass * 256;
        f4_t acc[16];
        #pragma unroll
        for (int nt = 0; nt < 16; ++nt) acc[nt] = (f4_t){0.f, 0.f, 0.f, 0.f};

        for (int kc = 0; kc < 8; ++kc) {
            __syncthreads();
            {
                const h8_t* bsrc = (const h8_t*)(wih + (size_t)(n0 + tid) * 256 + kc * 32);
                #pragma unroll
                for (int c = 0; c < 4; ++c)
                    *(h8_t*)(Bs + tid * 40 + c * 8) = bsrc[c];
            }
            __syncthreads();
            h8_t a = *(const h8_t*)(As + (wave * 16 + l15) * 264 + kc * 32 + quad * 8);
            #pragma unroll
            for (int nt = 0; nt < 16; ++nt) {
                h8_t b = *(const h8_t*)(Bs + (nt * 16 + l15) * 40 + quad * 8);
                acc[nt] = __builtin_amdgcn_mfma_f32_16x16x32_f16(a, b, acc[nt], 0, 0, 0);
            }
        }

        const size_t mbase = (size_t)bm * 64 + wave * 16 + quad * 4;
        #pragma unroll
        for (int nt = 0; nt < 16; ++nt) {
            const int col = n0 + nt * 16 + l15;
            #pragma unroll
            for (int r = 0; r < 4; ++r)
                gout[(mbase + r) * 1024 + col] = (_Float16)acc[nt][r];
        }
    }
}

// ---------------------------------------------------------------------------
// Kernel B: pairwise persistent LSTM, K-SPLIT: 256 blocks x 1024 threads.
// Round-1 champion structure (893us) with the per-thread work split along K:
// thread (khalf = q>>9, qr = q&511) owns gate row qr for k in
// [khalf*128, khalf*128+128). Why:
//  * weights/thread 128 -> 64 VGPRs — under the measured remat threshold
//    (R5: 64-reg arrays stay resident; R1/R9: 128-reg arrays get reloaded
//    every step, ~2x VALU inflation, VGPR capped at 88);
//  * 1024-thread block => 4 waves/SIMD (vs 2) — hides the dot2 dependency
//    chains and any residual L2 latency;
//  * h-broadcast LDS reads stay wave-uniform (khalf uniform per wave).
// Partial sums meet in gbuf[1024]; activation (q<128) sums both halves.
// Mailbox identical to R1 (pairwise, sentinel 0xFFFFFFFF = fp16 NaN pair,
// relaxed agent-scope atomics; all 256 blocks co-resident at 1 block/CU
// => spin cannot deadlock).
// ---------------------------------------------------------------------------
#define DOT8H(WC, HV, ACC) do {                                     \
    ACC = dot2(get2<0>(WC), get2<0>(HV), ACC);                      \
    ACC = dot2(get2<1>(WC), get2<1>(HV), ACC);                      \
    ACC = dot2(get2<2>(WC), get2<2>(HV), ACC);                      \
    ACC = dot2(get2<3>(WC), get2<3>(HV), ACC);                      \
} while (0)

#define VBLK(V) do {                                                \
    h8_t hv0 = HBk[(V)*4+0], hv1 = HBk[(V)*4+1];                    \
    h8_t hv2 = HBk[(V)*4+2], hv3 = HBk[(V)*4+3];                    \
    DOT8H(W##V##_0, hv0, a0); DOT8H(W##V##_1, hv1, a1);             \
    DOT8H(W##V##_2, hv2, a2); DOT8H(W##V##_3, hv3, a3);             \
} while (0)

#define LDW(V)                                                      \
    h8_t W##V##_0 = b8k[((V) * 512 + qr) * 4 + 0],                  \
         W##V##_1 = b8k[((V) * 512 + qr) * 4 + 1],                  \
         W##V##_2 = b8k[((V) * 512 + qr) * 4 + 2],                  \
         W##V##_3 = b8k[((V) * 512 + qr) * 4 + 3]

__global__ __attribute__((amdgpu_flat_work_group_size(1024, 1024),
                          amdgpu_waves_per_eu(4, 4)))
void lstm_pair(const _Float16* __restrict__ gin_f,
               const _Float16* __restrict__ gin_b,
               const _Float16* __restrict__ wreg2,
               const float* __restrict__ b_f,
               const float* __restrict__ b_b,
               float* __restrict__ hf, float* __restrict__ hb,
               unsigned int* __restrict__ hex)
{
    __shared__ h8_t  hbuf8[32];       // h(t) as 256 fp16
    __shared__ float gbuf[1024];      // [khalf][row] partial gate sums

    const int bid  = blockIdx.x;
    const int c16  = bid >> 4;
    const int w16  = bid & 15;
    const int half = w16 >> 3;                 // partner = bid ^ 8
    const int pair = c16 * 8 + (w16 & 7);      // 0..127
    const int dir  = pair >> 6;
    const int b    = pair & 63;
    const int q    = threadIdx.x;              // 0..1023
    const int khalf = q >> 9;                  // wave-uniform
    const int qr    = q & 511;

    const int gcl = qr >> 7, off = qr & 127;
    const int row = gcl * 256 + half * 128 + off;

    const _Float16* __restrict__ gin  = dir ? gin_b : gin_f;
    const float*    __restrict__ bs   = dir ? b_b : b_f;
    float*          __restrict__ hout = dir ? hb : hf;

    // register-resident weight half-row: 16 x h8 = 64 VGPRs
    const h8_t* b8k = (const h8_t*)wreg2 + (size_t)(dir * 2 + half) * 16384
                                          + (size_t)khalf * 8192;
    LDW(0); LDW(1); LDW(2); LDW(3);

    const float bias = bs[row];

    if (q < 32) hbuf8[q] = (h8_t)(_Float16)0.f;
    float c = 0.f;
    __syncthreads();

    const long tstr = 64 * 1024;
    const long hstr = 64 * 256;
    const int  t0   = dir ? (T_ - 1) : 0;
    const _Float16* gp = gin + (size_t)t0 * tstr + (size_t)b * 1024 + row;
    float*          hp = hout + (size_t)t0 * hstr + (size_t)b * 256 + half * 128 + q;
    const long gstep = dir ? -tstr : tstr;
    const long hstep = dir ? -hstr : hstr;

    // mailbox: 128 uints per pair per step = [pair][s][half][64]
    unsigned int* hexPub = hex + (size_t)pair * 65536 + (size_t)half * 64 + (q >> 1);
    const int pollw = (q >= 128 && q < 192);
    const int pi = pollw ? (q - 128) : 0;
    const unsigned int* hexPoll =
        hex + (size_t)pair * 65536 + (size_t)(1 - half) * 64 + pi;
    const int pdst = (1 - half) * 64 + pi;

    const h8_t* HBk = hbuf8 + khalf * 16;      // this thread's 128-h window
    unsigned int* hbufU = (unsigned int*)hbuf8;
    _Float16*    hbufH = (_Float16*)hbuf8;

    _Float16 gc0 = (_Float16)0.f;
    if (!khalf) gc0 = gp[0];

    for (int s = 0; s < T_; ++s) {
        _Float16 gn0 = (_Float16)0.f;
        if (!khalf) gn0 = gp[gstep];   // prefetch; safe overread on last step

        float a0 = 0.f, a1 = 0.f, a2 = 0.f, a3 = 0.f;
        VBLK(0); VBLK(1); VBLK(2); VBLK(3);

        float part = (a0 + a1) + (a2 + a3);
        if (!khalf) part += bias + (float)gc0;
        gbuf[q] = part;
        __syncthreads();

        if (q < 128) {
            float gi = gbuf[q]       + gbuf[q + 512];
            float gf = gbuf[q + 128] + gbuf[q + 640];
            float gg = gbuf[q + 256] + gbuf[q + 768];
            float go = gbuf[q + 384] + gbuf[q + 896];
            float si = 1.f / (1.f + expf(-gi));
            float sf = 1.f / (1.f + expf(-gf));
            float so = 1.f / (1.f + expf(-go));
            c = sf * c + si * tanhf(gg);
            float h = so * tanhf(c);
            hp[0] = h;
            hbufH[half * 128 + q] = (_Float16)h;
            if (s < T_ - 1) {
                float hn = __shfl_down(h, 1, 64);   // pairs never straddle a wave
                if ((q & 1) == 0) {
                    h2_t pk; pk[0] = (_Float16)h; pk[1] = (_Float16)hn;
                    __hip_atomic_store(hexPub + (size_t)s * 128,
                                       __builtin_bit_cast(unsigned int, pk),
                                       __ATOMIC_RELAXED, __HIP_MEMORY_SCOPE_AGENT);
                }
            }
        } else if (pollw && s < T_ - 1) {
            const unsigned int* src = hexPoll + (size_t)s * 128;
            unsigned int u;
            int guard = 0;
            do {
                u = __hip_atomic_load(src, __ATOMIC_RELAXED,
                                      __HIP_MEMORY_SCOPE_AGENT);
            } while (u == 0xFFFFFFFFu && ++guard < (1 << 20));
            hbufU[pdst] = u;
        }
        gc0 = gn0;
        gp += gstep;
        hp += hstep;
        __syncthreads();
    }
}

// ---------------------------------------------------------------------------
// Kernel C: feats[m, o] = concat(hf[m], hb[m]) . w_out[o, :] + b_out[o]
// ---------------------------------------------------------------------------
__global__ __launch_bounds__(256)
void feats_proj(const float* __restrict__ hf, const float* __restrict__ hb,
                const float* __restrict__ w_out, const float* __restrict__ b_out,
                float* __restrict__ feats)
{
    const int lane = threadIdx.x & 63;
    const int wv   = threadIdx.x >> 6;
    const int m    = blockIdx.x * 4 + wv;
    const int o    = lane & 15;
    const int qq   = lane >> 4;

    const float* hsrc = (qq < 2) ? (hf + (size_t)m * 256 + qq * 128)
                                 : (hb + (size_t)m * 256 + (qq - 2) * 128);
    const float4* h4 = (const float4*)hsrc;
    const float4* w4 = (const float4*)(w_out + o * 512 + qq * 128);

    float acc = 0.f;
    #pragma unroll
    for (int i = 0; i < 32; ++i) {
        float4 hv = h4[i], wvv = w4[i];
        acc = fmaf(hv.x, wvv.x, acc);
        acc = fmaf(hv.y, wvv.y, acc);
        acc = fmaf(hv.z, wvv.z, acc);
        acc = fmaf(hv.w, wvv.w, acc);
    }
    acc += __shfl_xor(acc, 16, 64);
    acc += __shfl_xor(acc, 32, 64);
    if (lane < 16) feats[(size_t)m * 16 + o] = acc + b_out[o];
}

// ---------------------------------------------------------------------------
// Kernel D: Viterbi + backtrace.
// ---------------------------------------------------------------------------
__global__ __launch_bounds__(64)
void viterbi(const float* __restrict__ feats, const float* __restrict__ trans,
             float* __restrict__ out)
{
    __shared__ unsigned char bp[T_][16];
    const int b    = blockIdx.x;
    const int lane = threadIdx.x;
    const int l15  = lane & 15;

    float tr[16];
    #pragma unroll
    for (int p = 0; p < 16; ++p)
        tr[p] = (lane < 16) ? trans[lane * 16 + p] : 0.f;

    float fv = (lane == START_) ? 0.f : NEG_;

    for (int t4 = 0; t4 < T_; t4 += 4) {
        float fblk = feats[((size_t)(t4 + (lane >> 4)) * 64 + b) * 16 + l15];
        #pragma unroll
        for (int tt = 0; tt < 4; ++tt) {
            const int t = t4 + tt;
            float best = -3.4e38f; int arg = 0;
            #pragma unroll
            for (int p = 0; p < 16; ++p) {
                float s = __shfl(fv, p, 64) + tr[p];
                if (s > best) { best = s; arg = p; }
            }
            float ft = __shfl(fblk, tt * 16 + l15, 64);
            if (lane < 16) {
                fv = best + ft;
                bp[t][lane] = (unsigned char)arg;
            }
        }
    }

    float term = fv + ((lane < 16) ? trans[STOP_ * 16 + lane] : 0.f);
    float v  = (lane < 16) ? term : -3.4e38f;
    int  idx = (lane < 16) ? lane : (1 << 20);
    #pragma unroll
    for (int off = 1; off < 64; off <<= 1) {
        float v2 = __shfl_xor(v, off, 64);
        int   i2 = __shfl_xor(idx, off, 64);
        if (v2 > v || (v2 == v && i2 < idx)) { v = v2; idx = i2; }
    }
    __syncthreads();
    if (lane == 0) {
        out[b] = v;
        int tag = idx;
        for (int t = T_ - 1; t >= 0; --t) {
            out[64 + (size_t)t * 64 + b] = (float)tag;
            tag = bp[t][tag];
        }
    }
}

// ---------------------------------------------------------------------------
extern "C" void kernel_launch(void* const* d_in, const int* in_sizes, int n_in,
                              void* d_out, int out_size, void* d_ws, size_t ws_size,
                              hipStream_t stream) {
    const int*   sentence = (const int*)d_in[0];
    const float* emb      = (const float*)d_in[1];
    const float* w_ih_f   = (const float*)d_in[2];
    const float* w_hh_f   = (const float*)d_in[3];
    const float* b_f      = (const float*)d_in[4];
    const float* w_ih_b   = (const float*)d_in[5];
    const float* w_hh_b   = (const float*)d_in[6];
    const float* b_b      = (const float*)d_in[7];
    const float* w_out    = (const float*)d_in[8];
    const float* b_out    = (const float*)d_in[9];
    const float* trans    = (const float*)d_in[10];
    float* out = (float*)d_out;

    // workspace: gin_f|gin_b (fp16 64MB ea) | hf|hb (fp32 32MB ea) |
    //            feats (2MB) | wih16 (1MB) | wreg2 (1MB) | hex mailbox (32MB)
    _Float16* gin_f = (_Float16*)d_ws;
    _Float16* gin_b = gin_f + (size_t)T_ * B_ * G_;
    float* hf    = (float*)(gin_b + (size_t)T_ * B_ * G_);
    float* hb    = hf + (size_t)T_ * B_ * H_;
    float* feats = hb + (size_t)T_ * B_ * H_;
    _Float16* wih16 = (_Float16*)(feats + (size_t)T_ * B_ * K_);
    _Float16* wreg2 = wih16 + 524288;
    unsigned int* hex = (unsigned int*)(wreg2 + 524288);

    prep_weights<<<320, 256, 0, stream>>>(w_hh_f, w_hh_b, w_ih_f, w_ih_b,
                                          wreg2, wih16);
    gates_mfma<<<dim3(512, 2), 256, 0, stream>>>(sentence, emb, wih16,
                                                 gin_f, gin_b);
    hipMemsetAsync(hex, 0xFF, (size_t)33554432, stream);   // prime sentinels
    lstm_pair<<<256, 1024, 0, stream>>>(gin_f, gin_b, wreg2, b_f, b_b,
                                        hf, hb, hex);
    feats_proj<<<8192, 256, 0, stream>>>(hf, hb, w_out, b_out, feats);
    viterbi<<<64, 64, 0, stream>>>(feats, trans, out);
}